// Round 5
// baseline (397.434 us; speedup 1.0000x reference)
//
#include <hip/hip_runtime.h>
#include <stdint.h>

#define K_ 8
#define N_ 512
#define NE_ 256
#define MA_ 3
#define IN_ 128
#define B_ 1024
#define STATE_ 2560
#define UNFOLDS_ 6
#define DT_ (0.04f / 6.0f)

typedef __attribute__((ext_vector_type(8))) short short8;   // 8 bf16 (4 VGPRs)
typedef __attribute__((ext_vector_type(4))) float floatx4;  // MFMA C/D

__device__ __forceinline__ float b2f(uint16_t u) {
    union { uint32_t i; float f; } v; v.i = ((uint32_t)u) << 16; return v.f;
}
__device__ __forceinline__ uint16_t f2b(float f) {
    union { float f; uint32_t i; } v; v.f = f;
    uint32_t i = v.i;
    uint32_t r = i + 0x7FFFu + ((i >> 16) & 1u);   // RTNE
    return (uint16_t)(r >> 16);
}
__device__ __forceinline__ uint32_t pack2(uint16_t lo, uint16_t hi) {
    return (uint32_t)lo | ((uint32_t)hi << 16);
}
// dtype-adaptive load: f32!=0 -> buffer is float32, else bf16
__device__ __forceinline__ float loadf(const void* p, size_t i, int f32) {
    return f32 ? ((const float*)p)[i] : b2f(((const uint16_t*)p)[i]);
}
// non-temporal variant (state/input streams must not evict Wsw from L2)
__device__ __forceinline__ float ntloadf(const void* p, size_t i, int f32) {
    return f32 ? __builtin_nontemporal_load((const float*)p + i)
               : b2f(__builtin_nontemporal_load((const uint16_t*)p + i));
}
__device__ __forceinline__ float spf(float x) {   // softplus, stable
    return (x > 20.f) ? x : log1pf(expf(x));
}
__device__ __forceinline__ float psig(float x) {
    // S_a=0.9, S_c=0: x1=-0.55 x2=-0.45 x3=0.45 x4=0.55, k=5
    float t1 = x + 0.55f;
    float q1 = 5.f * t1 * t1;
    float t2 = x - 0.55f;
    float q2 = 1.f - 5.f * t2 * t2;
    float out = (x < -0.55f) ? 0.f : q1;
    out = (x >= -0.45f) ? (x + 0.5f) : out;
    out = (x > 0.45f) ? q2 : out;
    out = (x > 0.55f) ? 1.f : out;
    return out;
}

// ---------------- dtype detector (verified working) ----------------
__global__ void srnn_detect_kernel(const uint16_t* canary, int* flag) {
    __shared__ int cnt;
    if (threadIdx.x == 0) cnt = 0;
    __syncthreads();
    int bad = 0;
    for (int i = threadIdx.x; i < 4096; i += 256) {
        uint16_t u = canary[i];
        int e = (u >> 7) & 0xFF;
        if (e >= 0xC0) bad++;
    }
    atomicAdd(&cnt, bad);
    __syncthreads();
    if (threadIdx.x == 0) flag[0] = (cnt >= 16) ? 1 : 0;
}

// ---------------- per-(k,n) fused constants (12 rows) ----------------
__global__ void srnn_params_kernel(
    const void* a0, const void* ltd,
    const void* ltaE, const void* lcE, const void* c0E,
    const void* ltaI, const void* lcI, const void* c0I,
    const void* lbrecE, const void* lbrelE,
    const void* lbrecI, const void* lbrelI,
    const int* flag, float* P)
{
    const int f = flag[0];
    int idx = blockIdx.x * 256 + threadIdx.x;
    if (idx >= K_ * N_) return;
    int n = idx & (N_ - 1);
    int k = idx >> 9;
    float gx = DT_ / spf(loadf(ltd, idx, f));
    float thr0 = loadf(a0, idx, f);

    const void *lta, *lc, *c0, *lbrec, *lbrel;
    int nn;
    if (n < NE_) { nn = n;        lta = ltaE; lc = lcE; c0 = c0E; lbrec = lbrecE; lbrel = lbrelE; }
    else         { nn = n - NE_;  lta = ltaI; lc = lcI; c0 = c0I; lbrec = lbrecI; lbrel = lbrelI; }
    int base3 = (k * NE_ + nn) * MA_;
    int base1 = k * NE_ + nn;

    float amul[3], ainv[3];
    #pragma unroll
    for (int j = 0; j < 3; ++j) {
        float ga = DT_ / spf(loadf(lta, base3 + j, f));
        float c  = spf(loadf(lc, base3 + j, f));
        amul[j] = ga * c;
        ainv[j] = 1.f / (1.f + ga);
        thr0 += loadf(c0, base3 + j, f);
    }
    float grec = DT_ / spf(loadf(lbrec, base1, f));
    float grel = DT_ / spf(loadf(lbrel, base1, f));

    const int KN = K_ * N_;
    P[0*KN + idx] = gx;
    P[1*KN + idx] = 1.f / (1.f + gx);
    P[2*KN + idx] = thr0;
    P[3*KN + idx] = grec;
    P[4*KN + idx] = grel;
    P[5*KN + idx] = amul[0]; P[6*KN + idx] = amul[1]; P[7*KN + idx] = amul[2];
    P[8*KN + idx] = ainv[0]; P[9*KN + idx] = ainv[1]; P[10*KN + idx] = ainv[2];
    P[11*KN + idx] = 1.f + grec;          // precomputed for bv denominator
}

// ---------------- W_eff swizzled into MFMA A-fragment order (verified) ----------------
// Wsw[k][nt 0..31][ks 0..15][lane 0..63][j 0..7] (bf16):
//   A[row = lane&15][kk = (lane>>4)*8 + j]; n = nt*16+row, m = ks*32+kk.
__global__ __launch_bounds__(256) void srnn_wsw_kernel(
    const void* __restrict__ Wraw, const void* __restrict__ mask,
    const int* __restrict__ flag, uint16_t* __restrict__ Wsw)
{
    __shared__ float tile[16 * 516];
    const int f = flag[0];
    const int nt = blockIdx.x, k = blockIdx.y, t = threadIdx.x;
    const size_t base = (size_t)k * N_ * N_ + (size_t)nt * 16 * N_;
    #pragma unroll
    for (int i = 0; i < 32; ++i) {
        int idx = i * 256 + t;
        int row = idx >> 9, m = idx & 511;
        size_t gi = base + (size_t)row * N_ + m;
        float w = spf(ntloadf(Wraw, gi, f)) * ntloadf(mask, gi, f);
        if (m >= NE_) w = -w;           // sign by SOURCE column m
        tile[row * 516 + m] = w;
    }
    __syncthreads();
    uint16_t* outb = Wsw + ((size_t)k * 32 + nt) * (16 * 64 * 8);
    #pragma unroll
    for (int i = 0; i < 4; ++i) {
        int id = i * 256 + t;           // 0..1023 = ks*64 + L
        int ks = id >> 6, L = id & 63;
        int row = L & 15, quad = L >> 4;
        const float* src = &tile[row * 516 + ks * 32 + quad * 8];
        uint4 v;
        v.x = pack2(f2b(src[0]), f2b(src[1]));
        v.y = pack2(f2b(src[2]), f2b(src[3]));
        v.z = pack2(f2b(src[4]), f2b(src[5]));
        v.w = pack2(f2b(src[6]), f2b(src[7]));
        *(uint4*)(outb + (size_t)id * 8) = v;
    }
}

// ---------------- W_in swizzled into MFMA A-fragment order ----------------
// Winsw[k][nt 0..31][ks 0..3][lane][8] (bf16): same mapping, kk-range = IN (128).
__global__ __launch_bounds__(256) void srnn_winsw_kernel(
    const void* __restrict__ Win, const int* __restrict__ flag,
    uint16_t* __restrict__ Winsw)
{
    __shared__ float tile[16 * 132];
    const int f = flag[0];
    const int nt = blockIdx.x, k = blockIdx.y, t = threadIdx.x;
    const size_t base = (size_t)k * N_ * IN_ + (size_t)nt * 16 * IN_;
    #pragma unroll
    for (int i = 0; i < 8; ++i) {
        int idx = i * 256 + t;          // 0..2047
        int row = idx >> 7, c = idx & 127;
        tile[row * 132 + c] = ntloadf(Win, base + (size_t)row * IN_ + c, f);
    }
    __syncthreads();
    uint16_t* outb = Winsw + ((size_t)k * 32 + nt) * (4 * 64 * 8);
    {
        int id = t;                     // 0..255 = ks*64 + L
        int ks = id >> 6, L = id & 63;
        int row = L & 15, quad = L >> 4;
        const float* src = &tile[row * 132 + ks * 32 + quad * 8];
        uint4 v;
        v.x = pack2(f2b(src[0]), f2b(src[1]));
        v.y = pack2(f2b(src[2]), f2b(src[3]));
        v.z = pack2(f2b(src[4]), f2b(src[5]));
        v.w = pack2(f2b(src[6]), f2b(src[7]));
        *(uint4*)(outb + (size_t)id * 8) = v;
    }
}

// ---------------- main persistent-state MFMA kernel ----------------
// grid 256 (= #CUs): k = bx&7 (XCD-pinned), btile = bx>>3 (32 b-columns).
// 1024 thr = 16 waves = 4 waves/SIMD -> HARD cap 128 regs/wave (incl AGPR).
// Round-5 change vs the verified round-3 kernel: LDS buffers sT/U/xL move to
// POWER-OF-2 row strides with a 3-bit XOR swizzle on the row index (T2
// pattern): elem ^= (row&7)<<3 for bf16 (16B slot = 8 elems), (row&7)<<2 for
// f32.  Both the write side and the read side apply the same key (key = the
// batch-row coordinate of the address), so the permutation is a consistent
// involution.  This breaks the 8-bank clustering of the GEMM's ds_read_b128
// B-fragment reads and the xL floatx4 RMW (old strides 520/516 gave dword
// stride ≡ 4 mod 32).  No register or semantic change otherwise.
__global__ __launch_bounds__(1024, 4)
void srnn_main_kernel(const void* __restrict__ state,
                      const void* __restrict__ inputs,
                      const uint16_t* __restrict__ Wsw,
                      const uint16_t* __restrict__ Winsw,
                      const float* __restrict__ P,
                      const int* __restrict__ readout,
                      const int* __restrict__ flag,
                      void* __restrict__ out)
{
    __shared__ __align__(16) uint16_t sT[2][16 * 512];   // [sub][b][m] bf16, swizzled
    __shared__ __align__(16) float xL[2][16 * 512];      // [sub][b][n] f32 x, swizzled
    __shared__ __align__(16) uint16_t U[2][16 * 128];    // [sub][b][i] bf16, swizzled
    __shared__ __align__(16) float Pl[12 * 512];         // per-n params (linear)

    const int f = flag[0];
    const int t = threadIdx.x;            // 0..1023
    const int k = blockIdx.x & 7;
    const int b0 = (blockIdx.x >> 3) * 32;
    const int sub = t >> 9;               // uniform per wave
    const int n = t & 511;
    const int lane = t & 63, w = t >> 6;  // w 0..15
    const int bq = lane & 15, quad = lane >> 4;
    const int bswz = (bq & 7) << 3;       // bf16 swizzle key (reader side)
    const int fswz = (bq & 7) << 2;       // f32 swizzle key (reader side)

    // ---- prologue staging ----
    {
        const int KN = K_ * N_;
        #pragma unroll
        for (int q = 0; q < 6; ++q) {
            int idx = q * 1024 + t;       // 0..6143
            Pl[idx] = P[(idx >> 9) * KN + k * N_ + (idx & 511)];
        }
    }
    #pragma unroll
    for (int q = 0; q < 4; ++q) {
        int idx = q * 1024 + t;           // 0..4095
        int ss = idx >> 11, rem = idx & 2047;
        int bb = rem >> 7, ii = rem & 127;
        U[ss][(bb * 128 + ii) ^ ((bb & 7) << 3)] =
            f2b(ntloadf(inputs, (size_t)(b0 + ss * 16 + bb) * IN_ + ii, f));
    }
    // persistent register state: a0,a1,a2,b (64 floats). x goes to LDS (swizzled).
    float a0v[16], a1v[16], a2v[16], bv[16];
    #pragma unroll
    for (int bb = 0; bb < 16; ++bb) {
        size_t sb = ((size_t)k * B_ + b0 + sub * 16 + bb) * STATE_;
        a0v[bb] = ntloadf(state, sb + 3 * n + 0, f);
        a1v[bb] = ntloadf(state, sb + 3 * n + 1, f);
        a2v[bb] = ntloadf(state, sb + 3 * n + 2, f);
        bv[bb]  = ntloadf(state, sb + 1536 + n, f);
        xL[sub][(bb * 512 + n) ^ ((bb & 7) << 2)] = ntloadf(state, sb + 2048 + n, f);
    }
    __syncthreads();

    // per-wave GEMM bases (nt = 2w, 2w+1); B/U reads apply ^bswz per access
    const uint16_t* sb0 = sT[0] + bq * 512;
    const uint16_t* sb1 = sT[1] + bq * 512;
    const uint16_t* ub0 = U[0] + bq * 128;
    const uint16_t* ub1 = U[1] + bq * 128;
    const uint16_t* ape  = Wsw + (size_t)k * 262144 + (size_t)(2 * w) * 8192
                               + (size_t)lane * 8;
    const uint16_t* apie = Winsw + (size_t)(k * 32 + 2 * w) * 2048
                                 + (size_t)lane * 8;
    // fused-x-update bases (C/D cols nb0/nb1 for nt=2w / 2w+1)
    const int nb0 = w * 32 + quad * 4;
    const int nb1 = nb0 + 16;

    for (int step = 0; step < UNFOLDS_; ++step) {
        // ---- elementwise (all waves; x read from LDS, NOT updated here) ----
        {
            const float thr0 = Pl[2*512+n], grec = Pl[3*512+n], grel = Pl[4*512+n];
            const float am0 = Pl[5*512+n], am1 = Pl[6*512+n], am2 = Pl[7*512+n];
            const float ai0 = Pl[8*512+n], ai1 = Pl[9*512+n], ai2 = Pl[10*512+n];
            const float ogr = Pl[11*512+n];
            #pragma unroll
            for (int bb = 0; bb < 16; ++bb) {
                float x = xL[sub][(bb * 512 + n) ^ ((bb & 7) << 2)];
                float thr = thr0 + a0v[bb] + a1v[bb] + a2v[bb];
                float r = psig(x - thr);
                float s = r * bv[bb];
                a0v[bb] = fmaf(am0, r, a0v[bb]) * ai0;
                a1v[bb] = fmaf(am1, r, a1v[bb]) * ai1;
                a2v[bb] = fmaf(am2, r, a2v[bb]) * ai2;
                bv[bb] = (bv[bb] + grec) *
                         __builtin_amdgcn_rcpf(fmaf(grel, r, ogr));
                sT[sub][(bb * 512 + n) ^ ((bb & 7) << 3)] = f2b(s);
            }
        }
        __syncthreads();

        // ---- single-pass GEMM, 4 accumulators; B-frags read once per ks ----
        {
            floatx4 c00 = {0.f,0.f,0.f,0.f}, c01 = c00, c10 = c00, c11 = c00;
            #pragma unroll 2
            for (int ks = 0; ks < 16; ++ks) {
                short8 bf0 = *(const short8*)(sb0 + ((quad * 8 + ks * 32) ^ bswz));
                short8 bf1 = *(const short8*)(sb1 + ((quad * 8 + ks * 32) ^ bswz));
                short8 af0 = *(const short8*)(ape + ks * 512);
                short8 af1 = *(const short8*)(ape + 8192 + ks * 512);
                c00 = __builtin_amdgcn_mfma_f32_16x16x32_bf16(af0, bf0, c00, 0, 0, 0);
                c01 = __builtin_amdgcn_mfma_f32_16x16x32_bf16(af0, bf1, c01, 0, 0, 0);
                c10 = __builtin_amdgcn_mfma_f32_16x16x32_bf16(af1, bf0, c10, 0, 0, 0);
                c11 = __builtin_amdgcn_mfma_f32_16x16x32_bf16(af1, bf1, c11, 0, 0, 0);
            }
            // in_cur extension: 4 K-slices over Winsw x U (identical f32 math
            // to adding a precomputed ic)
            #pragma unroll 2
            for (int e = 0; e < 4; ++e) {
                short8 bu0 = *(const short8*)(ub0 + ((quad * 8 + e * 32) ^ bswz));
                short8 bu1 = *(const short8*)(ub1 + ((quad * 8 + e * 32) ^ bswz));
                short8 aw0 = *(const short8*)(apie + e * 512);
                short8 aw1 = *(const short8*)(apie + 2048 + e * 512);
                c00 = __builtin_amdgcn_mfma_f32_16x16x32_bf16(aw0, bu0, c00, 0, 0, 0);
                c01 = __builtin_amdgcn_mfma_f32_16x16x32_bf16(aw0, bu1, c01, 0, 0, 0);
                c10 = __builtin_amdgcn_mfma_f32_16x16x32_bf16(aw1, bu0, c10, 0, 0, 0);
                c11 = __builtin_amdgcn_mfma_f32_16x16x32_bf16(aw1, bu1, c11, 0, 0, 0);
            }
            // fused x-update RMW: x = (x + gx*syn)*ivgx, exclusive per wave.
            // C/D layout: col = lane&15 (=b), row = quad*4 + reg (+16 for nt+1).
            floatx4 g0  = *(const floatx4*)&Pl[0*512 + nb0];
            floatx4 iv0 = *(const floatx4*)&Pl[1*512 + nb0];
            floatx4 g1  = *(const floatx4*)&Pl[0*512 + nb1];
            floatx4 iv1 = *(const floatx4*)&Pl[1*512 + nb1];
            float* p00 = &xL[0][bq * 512 + (nb0 ^ fswz)];
            float* p01 = &xL[1][bq * 512 + (nb0 ^ fswz)];
            float* p10 = &xL[0][bq * 512 + (nb1 ^ fswz)];
            float* p11 = &xL[1][bq * 512 + (nb1 ^ fswz)];
            floatx4 v;
            v = *(floatx4*)p00; v = (v + g0 * c00) * iv0; *(floatx4*)p00 = v;
            v = *(floatx4*)p01; v = (v + g0 * c01) * iv0; *(floatx4*)p01 = v;
            v = *(floatx4*)p10; v = (v + g1 * c10) * iv1; *(floatx4*)p10 = v;
            v = *(floatx4*)p11; v = (v + g1 * c11) * iv1; *(floatx4*)p11 = v;
        }
        __syncthreads();
    }

    // ---- epilogue: final rate_syn + stores (x already fully updated in xL) ----
    const int rid = readout[k];
    const float thr0e = Pl[2*512+n];
    if (f) {
        float* outp = (float*)out;
        float* nst = outp + (size_t)K_ * B_ * N_;
        #pragma unroll
        for (int bb = 0; bb < 16; ++bb) {
            float x = xL[sub][(bb * 512 + n) ^ ((bb & 7) << 2)];
            float thr = thr0e + a0v[bb] + a1v[bb] + a2v[bb];
            float r = psig(x - thr);
            float s = r * bv[bb];
            float o = (rid == 0) ? s : ((rid == 1) ? r : x);
            size_t ob = (size_t)k * B_ + b0 + sub * 16 + bb;
            __builtin_nontemporal_store(o, outp + ob * N_ + n);
            float* st = nst + ob * STATE_;
            __builtin_nontemporal_store(a0v[bb], st + 3 * n + 0);
            __builtin_nontemporal_store(a1v[bb], st + 3 * n + 1);
            __builtin_nontemporal_store(a2v[bb], st + 3 * n + 2);
            __builtin_nontemporal_store(bv[bb], st + 1536 + n);
            __builtin_nontemporal_store(x, st + 2048 + n);
        }
    } else {
        uint16_t* outp = (uint16_t*)out;
        uint16_t* nst = outp + (size_t)K_ * B_ * N_;
        #pragma unroll
        for (int bb = 0; bb < 16; ++bb) {
            float x = xL[sub][(bb * 512 + n) ^ ((bb & 7) << 2)];
            float thr = thr0e + a0v[bb] + a1v[bb] + a2v[bb];
            float r = psig(x - thr);
            float s = r * bv[bb];
            float o = (rid == 0) ? s : ((rid == 1) ? r : x);
            size_t ob = (size_t)k * B_ + b0 + sub * 16 + bb;
            __builtin_nontemporal_store(f2b(o), outp + ob * N_ + n);
            uint16_t* st = nst + ob * STATE_;
            __builtin_nontemporal_store(f2b(a0v[bb]), st + 3 * n + 0);
            __builtin_nontemporal_store(f2b(a1v[bb]), st + 3 * n + 1);
            __builtin_nontemporal_store(f2b(a2v[bb]), st + 3 * n + 2);
            __builtin_nontemporal_store(f2b(bv[bb]), st + 1536 + n);
            __builtin_nontemporal_store(f2b(x), st + 2048 + n);
        }
    }
}

extern "C" void kernel_launch(void* const* d_in, const int* in_sizes, int n_in,
                              void* d_out, int out_size, void* d_ws, size_t ws_size,
                              hipStream_t stream) {
    const void* inputs = d_in[0];
    const void* state  = d_in[1];
    const void* Wraw   = d_in[2];
    const void* mask   = d_in[3];
    const void* Win    = d_in[4];
    const void* a0     = d_in[5];
    const void* ltd    = d_in[6];
    const void* ltaE   = d_in[7];
    const void* lcE    = d_in[8];
    const void* c0E    = d_in[9];
    const void* ltaI   = d_in[10];
    const void* lcI    = d_in[11];
    const void* c0I    = d_in[12];
    const void* lbrecE = d_in[13];
    const void* lbrelE = d_in[14];
    const void* lbrecI = d_in[15];
    const void* lbrelI = d_in[16];
    const int* readout = (const int*)d_in[17];

    // workspace: flag 256 B | P 196,608 B (12 rows) | Wsw 4 MiB | Winsw 1 MiB
    char* ws = (char*)d_ws;
    int* flag       = (int*)ws;
    float* P        = (float*)(ws + 256);
    uint16_t* Wsw   = (uint16_t*)(ws + 256 + 196608);
    uint16_t* Winsw = (uint16_t*)(ws + 256 + 196608 + 4194304);

    srnn_detect_kernel<<<dim3(1), dim3(256), 0, stream>>>((const uint16_t*)Wraw, flag);
    srnn_params_kernel<<<dim3(16), dim3(256), 0, stream>>>(
        a0, ltd, ltaE, lcE, c0E, ltaI, lcI, c0I, lbrecE, lbrelE, lbrecI, lbrelI, flag, P);
    srnn_wsw_kernel<<<dim3(32, 8), dim3(256), 0, stream>>>(Wraw, mask, flag, Wsw);
    srnn_winsw_kernel<<<dim3(32, 8), dim3(256), 0, stream>>>(Win, flag, Winsw);
    srnn_main_kernel<<<dim3(256), dim3(1024), 0, stream>>>(
        state, inputs, Wsw, Winsw, P, readout, flag, d_out);
}

// Round 6
// 330.359 us; speedup vs baseline: 1.2030x; 1.2030x over previous
//
#include <hip/hip_runtime.h>
#include <stdint.h>

#define K_ 8
#define N_ 512
#define NE_ 256
#define MA_ 3
#define IN_ 128
#define B_ 1024
#define STATE_ 2560
#define UNFOLDS_ 6
#define DT_ (0.04f / 6.0f)

typedef __attribute__((ext_vector_type(8))) short short8;   // 8 bf16 (4 VGPRs)
typedef __attribute__((ext_vector_type(4))) float floatx4;  // MFMA C/D

__device__ __forceinline__ float b2f(uint16_t u) {
    union { uint32_t i; float f; } v; v.i = ((uint32_t)u) << 16; return v.f;
}
__device__ __forceinline__ uint16_t f2b(float f) {
    union { float f; uint32_t i; } v; v.f = f;
    uint32_t i = v.i;
    uint32_t r = i + 0x7FFFu + ((i >> 16) & 1u);   // RTNE
    return (uint16_t)(r >> 16);
}
__device__ __forceinline__ uint32_t pack2(uint16_t lo, uint16_t hi) {
    return (uint32_t)lo | ((uint32_t)hi << 16);
}
// dtype-adaptive load: f32!=0 -> buffer is float32, else bf16
__device__ __forceinline__ float loadf(const void* p, size_t i, int f32) {
    return f32 ? ((const float*)p)[i] : b2f(((const uint16_t*)p)[i]);
}
// non-temporal variant (state/input streams must not evict Wsw from L2)
__device__ __forceinline__ float ntloadf(const void* p, size_t i, int f32) {
    return f32 ? __builtin_nontemporal_load((const float*)p + i)
               : b2f(__builtin_nontemporal_load((const uint16_t*)p + i));
}
__device__ __forceinline__ float spf(float x) {   // softplus, stable
    return (x > 20.f) ? x : log1pf(expf(x));
}
__device__ __forceinline__ float psig(float x) {
    // S_a=0.9, S_c=0: x1=-0.55 x2=-0.45 x3=0.45 x4=0.55, k=5
    float t1 = x + 0.55f;
    float q1 = 5.f * t1 * t1;
    float t2 = x - 0.55f;
    float q2 = 1.f - 5.f * t2 * t2;
    float out = (x < -0.55f) ? 0.f : q1;
    out = (x >= -0.45f) ? (x + 0.5f) : out;
    out = (x > 0.45f) ? q2 : out;
    out = (x > 0.55f) ? 1.f : out;
    return out;
}

// ---------------- dtype detector (verified working) ----------------
__global__ void srnn_detect_kernel(const uint16_t* canary, int* flag) {
    __shared__ int cnt;
    if (threadIdx.x == 0) cnt = 0;
    __syncthreads();
    int bad = 0;
    for (int i = threadIdx.x; i < 4096; i += 256) {
        uint16_t u = canary[i];
        int e = (u >> 7) & 0xFF;
        if (e >= 0xC0) bad++;
    }
    atomicAdd(&cnt, bad);
    __syncthreads();
    if (threadIdx.x == 0) flag[0] = (cnt >= 16) ? 1 : 0;
}

// ---------------- per-(k,n) fused constants (12 rows) ----------------
__global__ void srnn_params_kernel(
    const void* a0, const void* ltd,
    const void* ltaE, const void* lcE, const void* c0E,
    const void* ltaI, const void* lcI, const void* c0I,
    const void* lbrecE, const void* lbrelE,
    const void* lbrecI, const void* lbrelI,
    const int* flag, float* P)
{
    const int f = flag[0];
    int idx = blockIdx.x * 256 + threadIdx.x;
    if (idx >= K_ * N_) return;
    int n = idx & (N_ - 1);
    int k = idx >> 9;
    float gx = DT_ / spf(loadf(ltd, idx, f));
    float thr0 = loadf(a0, idx, f);

    const void *lta, *lc, *c0, *lbrec, *lbrel;
    int nn;
    if (n < NE_) { nn = n;        lta = ltaE; lc = lcE; c0 = c0E; lbrec = lbrecE; lbrel = lbrelE; }
    else         { nn = n - NE_;  lta = ltaI; lc = lcI; c0 = c0I; lbrec = lbrecI; lbrel = lbrelI; }
    int base3 = (k * NE_ + nn) * MA_;
    int base1 = k * NE_ + nn;

    float amul[3], ainv[3];
    #pragma unroll
    for (int j = 0; j < 3; ++j) {
        float ga = DT_ / spf(loadf(lta, base3 + j, f));
        float c  = spf(loadf(lc, base3 + j, f));
        amul[j] = ga * c;
        ainv[j] = 1.f / (1.f + ga);
        thr0 += loadf(c0, base3 + j, f);
    }
    float grec = DT_ / spf(loadf(lbrec, base1, f));
    float grel = DT_ / spf(loadf(lbrel, base1, f));

    const int KN = K_ * N_;
    P[0*KN + idx] = gx;
    P[1*KN + idx] = 1.f / (1.f + gx);
    P[2*KN + idx] = thr0;
    P[3*KN + idx] = grec;
    P[4*KN + idx] = grel;
    P[5*KN + idx] = amul[0]; P[6*KN + idx] = amul[1]; P[7*KN + idx] = amul[2];
    P[8*KN + idx] = ainv[0]; P[9*KN + idx] = ainv[1]; P[10*KN + idx] = ainv[2];
    P[11*KN + idx] = 1.f + grec;          // precomputed for bv denominator
}

// ---------------- W_eff swizzled into MFMA A-fragment order (verified) ----------------
// Wsw[k][nt 0..31][ks 0..15][lane 0..63][j 0..7] (bf16):
//   A[row = lane&15][kk = (lane>>4)*8 + j]; n = nt*16+row, m = ks*32+kk.
__global__ __launch_bounds__(256) void srnn_wsw_kernel(
    const void* __restrict__ Wraw, const void* __restrict__ mask,
    const int* __restrict__ flag, uint16_t* __restrict__ Wsw)
{
    __shared__ float tile[16 * 516];
    const int f = flag[0];
    const int nt = blockIdx.x, k = blockIdx.y, t = threadIdx.x;
    const size_t base = (size_t)k * N_ * N_ + (size_t)nt * 16 * N_;
    #pragma unroll
    for (int i = 0; i < 32; ++i) {
        int idx = i * 256 + t;
        int row = idx >> 9, m = idx & 511;
        size_t gi = base + (size_t)row * N_ + m;
        float w = spf(ntloadf(Wraw, gi, f)) * ntloadf(mask, gi, f);
        if (m >= NE_) w = -w;           // sign by SOURCE column m
        tile[row * 516 + m] = w;
    }
    __syncthreads();
    uint16_t* outb = Wsw + ((size_t)k * 32 + nt) * (16 * 64 * 8);
    #pragma unroll
    for (int i = 0; i < 4; ++i) {
        int id = i * 256 + t;           // 0..1023 = ks*64 + L
        int ks = id >> 6, L = id & 63;
        int row = L & 15, quad = L >> 4;
        const float* src = &tile[row * 516 + ks * 32 + quad * 8];
        uint4 v;
        v.x = pack2(f2b(src[0]), f2b(src[1]));
        v.y = pack2(f2b(src[2]), f2b(src[3]));
        v.z = pack2(f2b(src[4]), f2b(src[5]));
        v.w = pack2(f2b(src[6]), f2b(src[7]));
        *(uint4*)(outb + (size_t)id * 8) = v;
    }
}

// ---------------- W_in swizzled into MFMA A-fragment order ----------------
// Winsw[k][nt 0..31][ks 0..3][lane][8] (bf16): same mapping, kk-range = IN (128).
__global__ __launch_bounds__(256) void srnn_winsw_kernel(
    const void* __restrict__ Win, const int* __restrict__ flag,
    uint16_t* __restrict__ Winsw)
{
    __shared__ float tile[16 * 132];
    const int f = flag[0];
    const int nt = blockIdx.x, k = blockIdx.y, t = threadIdx.x;
    const size_t base = (size_t)k * N_ * IN_ + (size_t)nt * 16 * IN_;
    #pragma unroll
    for (int i = 0; i < 8; ++i) {
        int idx = i * 256 + t;          // 0..2047
        int row = idx >> 7, c = idx & 127;
        tile[row * 132 + c] = ntloadf(Win, base + (size_t)row * IN_ + c, f);
    }
    __syncthreads();
    uint16_t* outb = Winsw + ((size_t)k * 32 + nt) * (4 * 64 * 8);
    {
        int id = t;                     // 0..255 = ks*64 + L
        int ks = id >> 6, L = id & 63;
        int row = L & 15, quad = L >> 4;
        const float* src = &tile[row * 132 + ks * 32 + quad * 8];
        uint4 v;
        v.x = pack2(f2b(src[0]), f2b(src[1]));
        v.y = pack2(f2b(src[2]), f2b(src[3]));
        v.z = pack2(f2b(src[4]), f2b(src[5]));
        v.w = pack2(f2b(src[6]), f2b(src[7]));
        *(uint4*)(outb + (size_t)id * 8) = v;
    }
}

// ---------------- main persistent-state MFMA kernel ----------------
// grid 256 (= #CUs): k = bx&7 (XCD-pinned), btile = bx>>3 (32 b-columns).
// 1024 thr = 16 waves = 4 waves/SIMD -> HARD cap 128 regs/wave (incl AGPR).
// Base = verified round-3 kernel (x state in LDS xL, fused RMW x-update).
// Round-6 change: in_cur (step-invariant) is computed ONCE in the prologue
// (same verified U-GEMM fragment code) and parked in LDS as bf16 (icL) at
// the accumulator's own C/D coordinates. The steady-state GEMM loses the
// 4 in_cur MFMA K-slices + 8 global loads per wave-step (-20% L2 A-stream)
// and their live temps; the RMW adds 4 uint2 LDS reads + unpack.
// U's staging buffer is aliased into sT (prologue-only lifetime).
__global__ __launch_bounds__(1024, 4)
void srnn_main_kernel(const void* __restrict__ state,
                      const void* __restrict__ inputs,
                      const uint16_t* __restrict__ Wsw,
                      const uint16_t* __restrict__ Winsw,
                      const float* __restrict__ P,
                      const int* __restrict__ readout,
                      const int* __restrict__ flag,
                      void* __restrict__ out)
{
    __shared__ __align__(16) uint16_t sT[2][16 * 520];   // [sub][b][m] bf16 (+U alias in prologue)
    __shared__ __align__(16) float xL[2][16 * 516];      // [sub][b][n] f32 x-state
    __shared__ __align__(16) uint16_t icL[2][16 * 520];  // [sub][b][n] bf16 in_cur
    __shared__ __align__(16) float Pl[12 * 512];         // per-n params

    const int f = flag[0];
    const int t = threadIdx.x;            // 0..1023
    const int k = blockIdx.x & 7;
    const int b0 = (blockIdx.x >> 3) * 32;
    const int sub = t >> 9;               // uniform per wave
    const int n = t & 511;
    const int lane = t & 63, w = t >> 6;  // w 0..15
    const int bq = lane & 15, quad = lane >> 4;

    // ---- prologue staging ----
    {
        const int KN = K_ * N_;
        #pragma unroll
        for (int q = 0; q < 6; ++q) {
            int idx = q * 1024 + t;       // 0..6143
            Pl[idx] = P[(idx >> 9) * KN + k * N_ + (idx & 511)];
        }
    }
    // inputs tile (transposed, bf16) into sT-alias (prologue-only lifetime)
    #pragma unroll
    for (int q = 0; q < 4; ++q) {
        int idx = q * 1024 + t;           // 0..4095
        int ss = idx >> 11, rem = idx & 2047;
        int bb = rem >> 7, ii = rem & 127;
        (ss ? sT[1] : sT[0])[bb * 136 + ii] =
            f2b(ntloadf(inputs, (size_t)(b0 + ss * 16 + bb) * IN_ + ii, f));
    }
    // persistent register state: a0,a1,a2,b (64 floats). x goes to LDS.
    float a0v[16], a1v[16], a2v[16], bv[16];
    #pragma unroll
    for (int bb = 0; bb < 16; ++bb) {
        size_t sb = ((size_t)k * B_ + b0 + sub * 16 + bb) * STATE_;
        a0v[bb] = ntloadf(state, sb + 3 * n + 0, f);
        a1v[bb] = ntloadf(state, sb + 3 * n + 1, f);
        a2v[bb] = ntloadf(state, sb + 3 * n + 2, f);
        bv[bb]  = ntloadf(state, sb + 1536 + n, f);
        xL[sub][bb * 516 + n] = ntloadf(state, sb + 2048 + n, f);
    }
    __syncthreads();

    // per-wave GEMM bases (nt = 2w, 2w+1)
    const uint16_t* bpe0 = sT[0] + bq * 520 + quad * 8;
    const uint16_t* bpe1 = sT[1] + bq * 520 + quad * 8;
    const uint16_t* ape  = Wsw + (size_t)k * 262144 + (size_t)(2 * w) * 8192
                               + (size_t)lane * 8;
    // fused-x-update coords (C/D cols nb0/nb1 for nt=2w / 2w+1)
    const int nb0 = w * 32 + quad * 4;
    const int nb1 = nb0 + 16;

    // ---- in_cur GEMM (once): Winsw x U -> icL (bf16, acc coordinates) ----
    {
        const uint16_t* upe0 = sT[0] + bq * 136 + quad * 8;
        const uint16_t* upe1 = sT[1] + bq * 136 + quad * 8;
        const uint16_t* apie = Winsw + (size_t)(k * 32 + 2 * w) * 2048
                                     + (size_t)lane * 8;
        floatx4 c00 = {0.f,0.f,0.f,0.f}, c01 = c00, c10 = c00, c11 = c00;
        #pragma unroll
        for (int e = 0; e < 4; ++e) {
            short8 bu0 = *(const short8*)(upe0 + e * 32);
            short8 bu1 = *(const short8*)(upe1 + e * 32);
            short8 aw0 = *(const short8*)(apie + e * 512);
            short8 aw1 = *(const short8*)(apie + 2048 + e * 512);
            c00 = __builtin_amdgcn_mfma_f32_16x16x32_bf16(aw0, bu0, c00, 0, 0, 0);
            c01 = __builtin_amdgcn_mfma_f32_16x16x32_bf16(aw0, bu1, c01, 0, 0, 0);
            c10 = __builtin_amdgcn_mfma_f32_16x16x32_bf16(aw1, bu0, c10, 0, 0, 0);
            c11 = __builtin_amdgcn_mfma_f32_16x16x32_bf16(aw1, bu1, c11, 0, 0, 0);
        }
        uint2 pv;
        pv.x = pack2(f2b(c00[0]), f2b(c00[1])); pv.y = pack2(f2b(c00[2]), f2b(c00[3]));
        *(uint2*)(icL[0] + bq * 520 + nb0) = pv;
        pv.x = pack2(f2b(c01[0]), f2b(c01[1])); pv.y = pack2(f2b(c01[2]), f2b(c01[3]));
        *(uint2*)(icL[1] + bq * 520 + nb0) = pv;
        pv.x = pack2(f2b(c10[0]), f2b(c10[1])); pv.y = pack2(f2b(c10[2]), f2b(c10[3]));
        *(uint2*)(icL[0] + bq * 520 + nb1) = pv;
        pv.x = pack2(f2b(c11[0]), f2b(c11[1])); pv.y = pack2(f2b(c11[2]), f2b(c11[3]));
        *(uint2*)(icL[1] + bq * 520 + nb1) = pv;
    }
    __syncthreads();   // U-alias dead; sT free for EW; icL visible

    for (int step = 0; step < UNFOLDS_; ++step) {
        // ---- elementwise (all waves; x read from LDS, NOT updated here) ----
        {
            const float thr0 = Pl[2*512+n], grec = Pl[3*512+n], grel = Pl[4*512+n];
            const float am0 = Pl[5*512+n], am1 = Pl[6*512+n], am2 = Pl[7*512+n];
            const float ai0 = Pl[8*512+n], ai1 = Pl[9*512+n], ai2 = Pl[10*512+n];
            const float ogr = Pl[11*512+n];
            #pragma unroll
            for (int bb = 0; bb < 16; ++bb) {
                float x = xL[sub][bb * 516 + n];
                float thr = thr0 + a0v[bb] + a1v[bb] + a2v[bb];
                float r = psig(x - thr);
                float s = r * bv[bb];
                a0v[bb] = fmaf(am0, r, a0v[bb]) * ai0;
                a1v[bb] = fmaf(am1, r, a1v[bb]) * ai1;
                a2v[bb] = fmaf(am2, r, a2v[bb]) * ai2;
                bv[bb] = (bv[bb] + grec) *
                         __builtin_amdgcn_rcpf(fmaf(grel, r, ogr));
                sT[sub][bb * 520 + n] = f2b(s);
            }
        }
        __syncthreads();

        // ---- single-pass GEMM, 4 accumulators; B-frags read once per ks ----
        {
            floatx4 c00 = {0.f,0.f,0.f,0.f}, c01 = c00, c10 = c00, c11 = c00;
            #pragma unroll 2
            for (int ks = 0; ks < 16; ++ks) {
                short8 bf0 = *(const short8*)(bpe0 + ks * 32);
                short8 bf1 = *(const short8*)(bpe1 + ks * 32);
                short8 af0 = *(const short8*)(ape + ks * 512);
                short8 af1 = *(const short8*)(ape + 8192 + ks * 512);
                c00 = __builtin_amdgcn_mfma_f32_16x16x32_bf16(af0, bf0, c00, 0, 0, 0);
                c01 = __builtin_amdgcn_mfma_f32_16x16x32_bf16(af0, bf1, c01, 0, 0, 0);
                c10 = __builtin_amdgcn_mfma_f32_16x16x32_bf16(af1, bf0, c10, 0, 0, 0);
                c11 = __builtin_amdgcn_mfma_f32_16x16x32_bf16(af1, bf1, c11, 0, 0, 0);
            }
            // fused x-update RMW: x = (x + gx*(syn+ic))*ivgx, exclusive per wave.
            // C/D layout: col = lane&15 (=b), row = quad*4 + reg (+16 for nt+1).
            uint2 q00 = *(const uint2*)(icL[0] + bq * 520 + nb0);
            uint2 q01 = *(const uint2*)(icL[1] + bq * 520 + nb0);
            uint2 q10 = *(const uint2*)(icL[0] + bq * 520 + nb1);
            uint2 q11 = *(const uint2*)(icL[1] + bq * 520 + nb1);
            floatx4 i00 = {b2f((uint16_t)q00.x), b2f((uint16_t)(q00.x >> 16)),
                           b2f((uint16_t)q00.y), b2f((uint16_t)(q00.y >> 16))};
            floatx4 i01 = {b2f((uint16_t)q01.x), b2f((uint16_t)(q01.x >> 16)),
                           b2f((uint16_t)q01.y), b2f((uint16_t)(q01.y >> 16))};
            floatx4 i10 = {b2f((uint16_t)q10.x), b2f((uint16_t)(q10.x >> 16)),
                           b2f((uint16_t)q10.y), b2f((uint16_t)(q10.y >> 16))};
            floatx4 i11 = {b2f((uint16_t)q11.x), b2f((uint16_t)(q11.x >> 16)),
                           b2f((uint16_t)q11.y), b2f((uint16_t)(q11.y >> 16))};
            floatx4 g0  = *(const floatx4*)&Pl[0*512 + nb0];
            floatx4 iv0 = *(const floatx4*)&Pl[1*512 + nb0];
            floatx4 g1  = *(const floatx4*)&Pl[0*512 + nb1];
            floatx4 iv1 = *(const floatx4*)&Pl[1*512 + nb1];
            float* p00 = &xL[0][bq * 516 + nb0];
            float* p01 = &xL[1][bq * 516 + nb0];
            float* p10 = &xL[0][bq * 516 + nb1];
            float* p11 = &xL[1][bq * 516 + nb1];
            floatx4 v;
            v = *(floatx4*)p00; v = (v + g0 * (c00 + i00)) * iv0; *(floatx4*)p00 = v;
            v = *(floatx4*)p01; v = (v + g0 * (c01 + i01)) * iv0; *(floatx4*)p01 = v;
            v = *(floatx4*)p10; v = (v + g1 * (c10 + i10)) * iv1; *(floatx4*)p10 = v;
            v = *(floatx4*)p11; v = (v + g1 * (c11 + i11)) * iv1; *(floatx4*)p11 = v;
        }
        __syncthreads();
    }

    // ---- epilogue: final rate_syn + stores (x already fully updated in xL) ----
    const int rid = readout[k];
    const float thr0e = Pl[2*512+n];
    if (f) {
        float* outp = (float*)out;
        float* nst = outp + (size_t)K_ * B_ * N_;
        #pragma unroll
        for (int bb = 0; bb < 16; ++bb) {
            float x = xL[sub][bb * 516 + n];
            float thr = thr0e + a0v[bb] + a1v[bb] + a2v[bb];
            float r = psig(x - thr);
            float s = r * bv[bb];
            float o = (rid == 0) ? s : ((rid == 1) ? r : x);
            size_t ob = (size_t)k * B_ + b0 + sub * 16 + bb;
            __builtin_nontemporal_store(o, outp + ob * N_ + n);
            float* st = nst + ob * STATE_;
            __builtin_nontemporal_store(a0v[bb], st + 3 * n + 0);
            __builtin_nontemporal_store(a1v[bb], st + 3 * n + 1);
            __builtin_nontemporal_store(a2v[bb], st + 3 * n + 2);
            __builtin_nontemporal_store(bv[bb], st + 1536 + n);
            __builtin_nontemporal_store(x, st + 2048 + n);
        }
    } else {
        uint16_t* outp = (uint16_t*)out;
        uint16_t* nst = outp + (size_t)K_ * B_ * N_;
        #pragma unroll
        for (int bb = 0; bb < 16; ++bb) {
            float x = xL[sub][bb * 516 + n];
            float thr = thr0e + a0v[bb] + a1v[bb] + a2v[bb];
            float r = psig(x - thr);
            float s = r * bv[bb];
            float o = (rid == 0) ? s : ((rid == 1) ? r : x);
            size_t ob = (size_t)k * B_ + b0 + sub * 16 + bb;
            __builtin_nontemporal_store(f2b(o), outp + ob * N_ + n);
            uint16_t* st = nst + ob * STATE_;
            __builtin_nontemporal_store(f2b(a0v[bb]), st + 3 * n + 0);
            __builtin_nontemporal_store(f2b(a1v[bb]), st + 3 * n + 1);
            __builtin_nontemporal_store(f2b(a2v[bb]), st + 3 * n + 2);
            __builtin_nontemporal_store(f2b(bv[bb]), st + 1536 + n);
            __builtin_nontemporal_store(f2b(x), st + 2048 + n);
        }
    }
}

extern "C" void kernel_launch(void* const* d_in, const int* in_sizes, int n_in,
                              void* d_out, int out_size, void* d_ws, size_t ws_size,
                              hipStream_t stream) {
    const void* inputs = d_in[0];
    const void* state  = d_in[1];
    const void* Wraw   = d_in[2];
    const void* mask   = d_in[3];
    const void* Win    = d_in[4];
    const void* a0     = d_in[5];
    const void* ltd    = d_in[6];
    const void* ltaE   = d_in[7];
    const void* lcE    = d_in[8];
    const void* c0E    = d_in[9];
    const void* ltaI   = d_in[10];
    const void* lcI    = d_in[11];
    const void* c0I    = d_in[12];
    const void* lbrecE = d_in[13];
    const void* lbrelE = d_in[14];
    const void* lbrecI = d_in[15];
    const void* lbrelI = d_in[16];
    const int* readout = (const int*)d_in[17];

    // workspace: flag 256 B | P 196,608 B (12 rows) | Wsw 4 MiB | Winsw 1 MiB
    char* ws = (char*)d_ws;
    int* flag       = (int*)ws;
    float* P        = (float*)(ws + 256);
    uint16_t* Wsw   = (uint16_t*)(ws + 256 + 196608);
    uint16_t* Winsw = (uint16_t*)(ws + 256 + 196608 + 4194304);

    srnn_detect_kernel<<<dim3(1), dim3(256), 0, stream>>>((const uint16_t*)Wraw, flag);
    srnn_params_kernel<<<dim3(16), dim3(256), 0, stream>>>(
        a0, ltd, ltaE, lcE, c0E, ltaI, lcI, c0I, lbrecE, lbrelE, lbrecI, lbrelI, flag, P);
    srnn_wsw_kernel<<<dim3(32, 8), dim3(256), 0, stream>>>(Wraw, mask, flag, Wsw);
    srnn_winsw_kernel<<<dim3(32, 8), dim3(256), 0, stream>>>(Win, flag, Winsw);
    srnn_main_kernel<<<dim3(256), dim3(1024), 0, stream>>>(
        state, inputs, Wsw, Winsw, P, readout, flag, d_out);
}